// Round 7
// baseline (271.285 us; speedup 1.0000x reference)
//
#include <hip/hip_runtime.h>

#define N_NODES 4096
#define HID 512
#define HEADS 8
#define DH 64
#define EPS 1e-5f
#define MAXD 128

typedef __attribute__((ext_vector_type(8))) short bf16x8;
typedef __attribute__((ext_vector_type(4))) float f32x4;

__device__ __forceinline__ unsigned short f2bf(float f) {
    unsigned int u = __float_as_uint(f);
    unsigned int r = (u + 0x7FFFu + ((u >> 16) & 1u)) >> 16;   // RNE
    return (unsigned short)r;
}
__device__ __forceinline__ float blo(unsigned int u) {        // low bf16 -> f32
    return __uint_as_float(u << 16);
}
__device__ __forceinline__ float bhi(unsigned int u) {        // high bf16 -> f32
    return __uint_as_float(u & 0xffff0000u);
}

// ---------------------------------------------------------------------------
// Single-wave barrier-free bf16 MFMA GEMM: C[M x Nc] = X[M x K] @ W^T
// (Wt[Nc][K] K-major). Block = ONE wave (64 thr) owning a TM x 64 tile.
// No LDS at all: each MFMA fragment is loaded straight global -> VGPR as an
// aligned 16B vector load (lane (lc,lq) reads row +lc, k-chunk lq — a
// single-wave tile has no cross-wave reuse, so LDS staging only added
// barriers; __syncthreads+vmcnt(0) drains were the R5/R6 GEMM bottleneck).
// Compiler pipelines these plain loads across K-iterations with fine vmcnt.
// Grids: 1024-2048 blocks -> 4-8 independent wave-pipelines per CU.
// EPI: 0 bias->bf16 ; 1 bias+relu->bf16 ; 2 bias+res(f32)->f32 + stats ;
//      3 bias+res(bf16)->f32 + stats
// ---------------------------------------------------------------------------
template<int TM, int EPI>
__global__ __launch_bounds__(64) void gemm_w1(
    const unsigned short* __restrict__ Xb, const unsigned short* __restrict__ Wt,
    const float* __restrict__ bias, const float* __restrict__ res,
    const unsigned short* __restrict__ resb,
    float* __restrict__ outf, unsigned short* __restrict__ outb,
    float* __restrict__ sum, float* __restrict__ sumsq,
    int K, int Nc)
{
    constexpr int WM = TM / 16;                  // 16x16 mfma row-tiles (2 or 4)
    const int lane = threadIdx.x;
    const int m0 = blockIdx.y * TM, n0 = blockIdx.x * 64;
    const int lc = lane & 15, lq = lane >> 4;

    // lane's base pointers: row +lc, k-offset lq*8 (16B aligned)
    const unsigned short* pa = Xb + (size_t)(m0 + lc) * K + lq * 8;
    const unsigned short* pb = Wt + (size_t)(n0 + lc) * K + lq * 8;

    f32x4 acc[WM][4] = {};

    for (int k0 = 0; k0 < K; k0 += 64) {
        bf16x8 af[WM][2], bfr[4][2];
        #pragma unroll
        for (int i = 0; i < WM; ++i)
            #pragma unroll
            for (int h = 0; h < 2; ++h)
                af[i][h] = *(const bf16x8*)(pa + (size_t)(i * 16) * K + k0 + h * 32);
        #pragma unroll
        for (int j = 0; j < 4; ++j)
            #pragma unroll
            for (int h = 0; h < 2; ++h)
                bfr[j][h] = *(const bf16x8*)(pb + (size_t)(j * 16) * K + k0 + h * 32);
        #pragma unroll
        for (int h = 0; h < 2; ++h)
            #pragma unroll
            for (int i = 0; i < WM; ++i)
                #pragma unroll
                for (int j = 0; j < 4; ++j)
                    acc[i][j] = __builtin_amdgcn_mfma_f32_16x16x32_bf16(
                        af[i][h], bfr[j][h], acc[i][j], 0, 0, 0);
    }

    float cs[4] = {}, css[4] = {};
    #pragma unroll
    for (int i = 0; i < WM; ++i) {
        #pragma unroll
        for (int j = 0; j < 4; ++j) {
            const int gr0 = m0 + i * 16 + lq * 4;
            const int gc = n0 + j * 16 + lc;
            const float bi = bias[gc];
            #pragma unroll
            for (int r = 0; r < 4; ++r) {
                float val = acc[i][j][r] + bi;
                size_t off = (size_t)(gr0 + r) * Nc + gc;
                if (EPI == 0)      outb[off] = f2bf(val);
                else if (EPI == 1) outb[off] = f2bf(fmaxf(val, 0.f));
                else {
                    if (EPI == 2) val += res[off];
                    else          val += blo((unsigned int)resb[off]);
                    outf[off] = val;
                    cs[j] += val; css[j] += val * val;
                }
            }
        }
    }
    if (EPI >= 2) {
        #pragma unroll
        for (int j = 0; j < 4; ++j) {
            float s = cs[j], ss = css[j];
            s += __shfl_xor(s, 16); s += __shfl_xor(s, 32);
            ss += __shfl_xor(ss, 16); ss += __shfl_xor(ss, 32);
            if (lq == 0) {
                const int gc = n0 + j * 16 + lc;
                atomicAdd(&sum[gc], s);
                atomicAdd(&sumsq[gc], ss);
            }
        }
    }
}

// ---------------------------------------------------------------------------
// Fused prep: z=0..5 weight transposes, z=6 h->bf16, z=7 bias concat + zero
// ---------------------------------------------------------------------------
__global__ __launch_bounds__(256) void prep_all(
    const float* __restrict__ Wq, const float* __restrict__ Wk,
    const float* __restrict__ Wv, const float* __restrict__ Wo,
    const float* __restrict__ W1, const float* __restrict__ W2,
    const float* __restrict__ h,
    const float* __restrict__ bq, const float* __restrict__ bk,
    const float* __restrict__ bv,
    unsigned short* __restrict__ wqkvT, unsigned short* __restrict__ woT,
    unsigned short* __restrict__ w1T, unsigned short* __restrict__ w2T,
    unsigned int* __restrict__ hb, float* __restrict__ bqkv,
    float* __restrict__ st)
{
    const int z = blockIdx.z;
    if (z < 6) {
        const float* in; unsigned short* out; int R, C;
        switch (z) {
            case 0: in = Wq; out = wqkvT;          R = 512;  C = 512;  break;
            case 1: in = Wk; out = wqkvT + 262144; R = 512;  C = 512;  break;
            case 2: in = Wv; out = wqkvT + 524288; R = 512;  C = 512;  break;
            case 3: in = Wo; out = woT;            R = 512;  C = 512;  break;
            case 4: in = W1; out = w1T;            R = 512;  C = 1024; break;
            default: in = W2; out = w2T;           R = 1024; C = 512;  break;
        }
        const int bc = blockIdx.x * 32, br = blockIdx.y * 32;
        if (bc >= C || br >= R) return;
        __shared__ float tile[32][33];
        const int tx = threadIdx.x & 31, ty = threadIdx.x >> 5;
        #pragma unroll
        for (int r = ty; r < 32; r += 8)
            tile[r][tx] = in[(size_t)(br + r) * C + bc + tx];
        __syncthreads();
        #pragma unroll
        for (int r = ty; r < 32; r += 8)
            out[(size_t)(bc + r) * R + br + tx] = f2bf(tile[tx][r]);
    } else if (z == 6) {
        const int blk = blockIdx.y * 32 + blockIdx.x;
        const int i = blk * 512 + threadIdx.x * 2;   // float4 index (524288 total)
        const float4* in4 = (const float4*)h;
        #pragma unroll
        for (int u = 0; u < 2; ++u) {
            float4 f = in4[i + u];
            hb[(i + u) * 2]     = (unsigned int)f2bf(f.x) | ((unsigned int)f2bf(f.y) << 16);
            hb[(i + u) * 2 + 1] = (unsigned int)f2bf(f.z) | ((unsigned int)f2bf(f.w) << 16);
        }
    } else {
        const int blk = blockIdx.y * 32 + blockIdx.x;
        const int i = blk * 256 + threadIdx.x;
        if (i < 1536) bqkv[i] = i < 512 ? bq[i] : (i < 1024 ? bk[i - 512] : bv[i - 1024]);
        if (i < 2048) st[i] = 0.0f;
    }
}

// ---------------------------------------------------------------------------
// Sparse attention v5 (unchanged from R6: 44us, 0 conflicts, matched preds).
// Inline adjacency build + dual-head gather loops with 1-deep prefetch.
// NO bulk K/V LDS staging (v3's 1-block/CU cliff: 123us vs 65us).
// ---------------------------------------------------------------------------
__global__ __launch_bounds__(256) void sparse_attn5(
    const float* __restrict__ A, const unsigned short* __restrict__ qkv,
    unsigned short* __restrict__ o)
{
    const int n = blockIdx.x;
    const int tid = threadIdx.x;
    const int wv = tid >> 6, lane = tid & 63;

    __shared__ int s_idx[MAXD];
    __shared__ float s_p[8][MAXD];
    __shared__ int s_cnt[4];

    // ---- Phase A: inline adjacency ----
    const float4* r4 = (const float4*)(A + (size_t)n * N_NODES);
    float4 av[4];
    #pragma unroll
    for (int t = 0; t < 4; ++t)
        av[t] = r4[wv * 256 + t * 64 + lane];

    const unsigned long long lt = (1ull << lane) - 1ull;
    int cnt = 0;
    #pragma unroll
    for (int t = 0; t < 4; ++t) {
        #pragma unroll
        for (int b = 0; b < 4; ++b) {
            float vb = (b == 0) ? av[t].x : (b == 1) ? av[t].y : (b == 2) ? av[t].z : av[t].w;
            cnt += __popcll(__ballot(vb > 0.0f));
        }
    }
    if (lane == 0) s_cnt[wv] = cnt;
    __syncthreads();
    int base = 0, total = 0;
    #pragma unroll
    for (int w = 0; w < 4; ++w) {
        if (w < wv) base += s_cnt[w];
        total += s_cnt[w];
    }
    const int d = total < MAXD ? total : MAXD;
    #pragma unroll
    for (int t = 0; t < 4; ++t) {
        #pragma unroll
        for (int b = 0; b < 4; ++b) {
            float vb = (b == 0) ? av[t].x : (b == 1) ? av[t].y : (b == 2) ? av[t].z : av[t].w;
            unsigned long long m = __ballot(vb > 0.0f);
            if (vb > 0.0f) {
                int p = base + __popcll(m & lt);
                if (p < MAXD) s_idx[p] = wv * 1024 + t * 256 + lane * 4 + b;
            }
            base += __popcll(m);
        }
    }
    __syncthreads();

    // ---- Phase B: attention ----
    const int jl = lane >> 3;
    const int dgs = lane & 7;
    const int jl2 = lane >> 4;
    const int dga = lane & 15;
    const int h0 = wv, h1 = wv + 4;

    const unsigned short* qp = qkv + (size_t)n * 1536 + dgs * 8;
    uint4 qa = *(const uint4*)(qp + h0 * 64);
    uint4 qb = *(const uint4*)(qp + h1 * 64);
    const float a0 = blo(qa.x), a1 = bhi(qa.x), a2 = blo(qa.y), a3 = bhi(qa.y);
    const float a4 = blo(qa.z), a5 = bhi(qa.z), a6 = blo(qa.w), a7 = bhi(qa.w);
    const float b0 = blo(qb.x), b1 = bhi(qb.x), b2 = blo(qb.y), b3 = bhi(qb.y);
    const float b4 = blo(qb.z), b5 = bhi(qb.z), b6 = blo(qb.w), b7 = bhi(qb.w);

    uint4 ka = {0, 0, 0, 0}, kb = {0, 0, 0, 0};
    if (jl < d) {
        const unsigned short* p = qkv + (size_t)s_idx[jl] * 1536 + 512 + dgs * 8;
        ka = *(const uint4*)(p + h0 * 64);
        kb = *(const uint4*)(p + h1 * 64);
    }
    for (int j0 = 0; j0 < d; j0 += 8) {
        const uint4 ca = ka, cb = kb;
        const int jn = j0 + 8 + jl;
        if (jn < d) {
            const unsigned short* p = qkv + (size_t)s_idx[jn] * 1536 + 512 + dgs * 8;
            ka = *(const uint4*)(p + h0 * 64);
            kb = *(const uint4*)(p + h1 * 64);
        }
        const int jc = j0 + jl;
        float s0 = 0.f, s1 = 0.f;
        if (jc < d) {
            s0 = a0 * blo(ca.x) + a1 * bhi(ca.x) + a2 * blo(ca.y) + a3 * bhi(ca.y)
               + a4 * blo(ca.z) + a5 * bhi(ca.z) + a6 * blo(ca.w) + a7 * bhi(ca.w);
            s1 = b0 * blo(cb.x) + b1 * bhi(cb.x) + b2 * blo(cb.y) + b3 * bhi(cb.y)
               + b4 * blo(cb.z) + b5 * bhi(cb.z) + b6 * blo(cb.w) + b7 * bhi(cb.w);
        }
        s0 += __shfl_xor(s0, 1); s1 += __shfl_xor(s1, 1);
        s0 += __shfl_xor(s0, 2); s1 += __shfl_xor(s1, 2);
        s0 += __shfl_xor(s0, 4); s1 += __shfl_xor(s1, 4);
        if (dgs == 0 && jc < d) {
            s_p[h0][jc] = s0 * 0.125f;
            s_p[h1][jc] = s1 * 0.125f;
        }
    }

    float inv0, inv1;
    #pragma unroll
    for (int hh = 0; hh < 2; ++hh) {
        float* sp = s_p[hh ? h1 : h0];
        float mx = -1e30f;
        for (int j = lane; j < d; j += 64) mx = fmaxf(mx, sp[j]);
        #pragma unroll
        for (int off = 32; off; off >>= 1) mx = fmaxf(mx, __shfl_xor(mx, off));
        float sum = 0.f;
        for (int j = lane; j < d; j += 64) {
            float e = __expf(sp[j] - mx);
            sp[j] = e;
            sum += e;
        }
        #pragma unroll
        for (int off = 32; off; off >>= 1) sum += __shfl_xor(sum, off);
        if (hh) inv1 = 1.0f / sum; else inv0 = 1.0f / sum;
    }

    float x0 = 0.f, x1 = 0.f, x2 = 0.f, x3 = 0.f;
    float y0 = 0.f, y1 = 0.f, y2 = 0.f, y3 = 0.f;
    uint2 va = {0, 0}, vb = {0, 0};
    if (jl2 < d) {
        const unsigned short* p = qkv + (size_t)s_idx[jl2] * 1536 + 1024 + dga * 4;
        va = *(const uint2*)(p + h0 * 64);
        vb = *(const uint2*)(p + h1 * 64);
    }
    for (int j0 = 0; j0 < d; j0 += 4) {
        const uint2 ca = va, cb = vb;
        const int jn = j0 + 4 + jl2;
        if (jn < d) {
            const unsigned short* p = qkv + (size_t)s_idx[jn] * 1536 + 1024 + dga * 4;
            va = *(const uint2*)(p + h0 * 64);
            vb = *(const uint2*)(p + h1 * 64);
        }
        const int jc = j0 + jl2;
        if (jc < d) {
            const float p0 = s_p[h0][jc], p1 = s_p[h1][jc];
            x0 += p0 * blo(ca.x); x1 += p0 * bhi(ca.x);
            x2 += p0 * blo(ca.y); x3 += p0 * bhi(ca.y);
            y0 += p1 * blo(cb.x); y1 += p1 * bhi(cb.x);
            y2 += p1 * blo(cb.y); y3 += p1 * bhi(cb.y);
        }
    }
    x0 += __shfl_xor(x0, 16); x0 += __shfl_xor(x0, 32);
    x1 += __shfl_xor(x1, 16); x1 += __shfl_xor(x1, 32);
    x2 += __shfl_xor(x2, 16); x2 += __shfl_xor(x2, 32);
    x3 += __shfl_xor(x3, 16); x3 += __shfl_xor(x3, 32);
    y0 += __shfl_xor(y0, 16); y0 += __shfl_xor(y0, 32);
    y1 += __shfl_xor(y1, 16); y1 += __shfl_xor(y1, 32);
    y2 += __shfl_xor(y2, 16); y2 += __shfl_xor(y2, 32);
    y3 += __shfl_xor(y3, 16); y3 += __shfl_xor(y3, 32);
    if (jl2 == 0) {
        uint2 w0, w1;
        w0.x = (unsigned int)f2bf(x0 * inv0) | ((unsigned int)f2bf(x1 * inv0) << 16);
        w0.y = (unsigned int)f2bf(x2 * inv0) | ((unsigned int)f2bf(x3 * inv0) << 16);
        w1.x = (unsigned int)f2bf(y0 * inv1) | ((unsigned int)f2bf(y1 * inv1) << 16);
        w1.y = (unsigned int)f2bf(y2 * inv1) | ((unsigned int)f2bf(y3 * inv1) << 16);
        *(uint2*)(o + (size_t)n * 512 + h0 * 64 + dga * 4) = w0;
        *(uint2*)(o + (size_t)n * 512 + h1 * 64 + dga * 4) = w1;
    }
}

// ---------------------------------------------------------------------------
// BatchNorm apply, float4 (stats fused in the preceding GEMM epilogue).
// ---------------------------------------------------------------------------
__global__ __launch_bounds__(256) void bn_apply4(
    const float4* __restrict__ x, const float* __restrict__ sum,
    const float* __restrict__ sumsq, const float* __restrict__ g,
    const float* __restrict__ b, float4* __restrict__ yf,
    uint2* __restrict__ yb)
{
    const int i = blockIdx.x * 256 + threadIdx.x;
    const int c4 = i & 127;
    const float4 s4 = ((const float4*)sum)[c4];
    const float4 q4 = ((const float4*)sumsq)[c4];
    const float4 g4 = ((const float4*)g)[c4];
    const float4 b4 = ((const float4*)b)[c4];
    const float4 xv = x[i];
    const float kN = 1.0f / N_NODES;
    float4 r;
    { float m = s4.x * kN; r.x = g4.x * (xv.x - m) * rsqrtf(q4.x * kN - m * m + EPS) + b4.x; }
    { float m = s4.y * kN; r.y = g4.y * (xv.y - m) * rsqrtf(q4.y * kN - m * m + EPS) + b4.y; }
    { float m = s4.z * kN; r.z = g4.z * (xv.z - m) * rsqrtf(q4.z * kN - m * m + EPS) + b4.z; }
    { float m = s4.w * kN; r.w = g4.w * (xv.w - m) * rsqrtf(q4.w * kN - m * m + EPS) + b4.w; }
    if (yf) yf[i] = r;
    if (yb) {
        uint2 p;
        p.x = (unsigned int)f2bf(r.x) | ((unsigned int)f2bf(r.y) << 16);
        p.y = (unsigned int)f2bf(r.z) | ((unsigned int)f2bf(r.w) << 16);
        yb[i] = p;
    }
}

// ---------------------------------------------------------------------------

extern "C" void kernel_launch(void* const* d_in, const int* in_sizes, int n_in,
                              void* d_out, int out_size, void* d_ws, size_t ws_size,
                              hipStream_t stream)
{
    const float* A   = (const float*)d_in[0];
    const float* h   = (const float*)d_in[1];
    const float* Wq  = (const float*)d_in[2];
    const float* bq  = (const float*)d_in[3];
    const float* Wk  = (const float*)d_in[4];
    const float* bk  = (const float*)d_in[5];
    const float* Wv  = (const float*)d_in[6];
    const float* bv  = (const float*)d_in[7];
    const float* Wo  = (const float*)d_in[8];
    const float* bo  = (const float*)d_in[9];
    const float* g1  = (const float*)d_in[10];
    const float* b1g = (const float*)d_in[11];
    const float* g2  = (const float*)d_in[12];
    const float* b2g = (const float*)d_in[13];
    const float* W1  = (const float*)d_in[14];
    const float* b1  = (const float*)d_in[15];
    const float* W2  = (const float*)d_in[16];
    const float* b2  = (const float*)d_in[17];
    float* out = (float*)d_out;

    float* ws = (float*)d_ws;
    unsigned short* hb    = (unsigned short*)(ws);               // 4096x512 bf16
    unsigned short* qkvb  = (unsigned short*)(ws + 1048576);     // 4096x1536 bf16
    unsigned short* o_bf  = (unsigned short*)(ws + 4194304);     // 4096x512 bf16
    unsigned short* wqkvT = (unsigned short*)(ws + 5242880);     // 1536x512 bf16
    unsigned short* woT   = (unsigned short*)(ws + 5636096);     // 512x512 bf16
    unsigned short* w1T   = (unsigned short*)(ws + 5767168);     // 1024x512 bf16
    unsigned short* w2T   = (unsigned short*)(ws + 6029312);     // 512x1024 bf16
    unsigned short* t_b   = (unsigned short*)(ws + 6291456);     // 4096x1024 bf16
    float* x1   = ws + 8388608;                                   // 4096x512 f32
    float* x2   = ws + 10485760;                                  // 4096x512 f32
    unsigned short* xb1_b = (unsigned short*)(ws + 12582912);    // 4096x512 bf16
    float* bqkv = ws + 13631488;                                  // 1536
    float* st   = ws + 13633024;                                  // 2048

    // --- fused prep ---
    prep_all<<<dim3(32, 32, 8), dim3(256), 0, stream>>>(
        Wq, Wk, Wv, Wo, W1, W2, h, bq, bk, bv,
        wqkvT, woT, w1T, w2T, (unsigned int*)hb, bqkv, st);

    // --- fused QKV projection: 1536 single-wave blocks (6/CU) ---
    gemm_w1<64, 0><<<dim3(24, 64), dim3(64), 0, stream>>>(
        hb, wqkvT, bqkv, nullptr, nullptr, nullptr, qkvb, nullptr, nullptr, 512, 1536);

    // --- sparse masked attention (inline adjacency) ---
    sparse_attn5<<<dim3(N_NODES), dim3(256), 0, stream>>>(A, qkvb, o_bf);

    // --- O projection + residual(h,f32) + BN1 stats: 1024 blocks (4/CU) ---
    gemm_w1<32, 2><<<dim3(8, 128), dim3(64), 0, stream>>>(
        o_bf, woT, bo, h, nullptr, x1, nullptr, st, st + 512, 512, 512);

    // --- BN1 apply -> bf16 only ---
    bn_apply4<<<dim3(2048), dim3(256), 0, stream>>>(
        (const float4*)x1, st, st + 512, g1, b1g, nullptr, (uint2*)xb1_b);

    // --- FFN1: 2048 blocks (8/CU) ---
    gemm_w1<32, 1><<<dim3(16, 128), dim3(64), 0, stream>>>(
        xb1_b, w1T, b1, nullptr, nullptr, nullptr, t_b, nullptr, nullptr, 512, 1024);

    // --- FFN2 + residual(xb1,bf16) + BN2 stats: 1024 blocks (4/CU) ---
    gemm_w1<32, 3><<<dim3(8, 128), dim3(64), 0, stream>>>(
        t_b, w2T, b2, nullptr, xb1_b, x2, nullptr, st + 1024, st + 1536, 1024, 512);

    // --- BN2 apply -> out ---
    bn_apply4<<<dim3(2048), dim3(256), 0, stream>>>(
        (const float4*)x2, st + 1024, st + 1536, g2, b2g, (float4*)out, nullptr);

    (void)in_sizes; (void)n_in; (void)out_size; (void)ws_size;
}

// Round 8
// 241.535 us; speedup vs baseline: 1.1232x; 1.1232x over previous
//
#include <hip/hip_runtime.h>

#define N_NODES 4096
#define HID 512
#define HEADS 8
#define DH 64
#define EPS 1e-5f
#define MAXD 128

typedef __attribute__((ext_vector_type(8))) short bf16x8;
typedef __attribute__((ext_vector_type(4))) float f32x4;

__device__ __forceinline__ unsigned short f2bf(float f) {
    unsigned int u = __float_as_uint(f);
    unsigned int r = (u + 0x7FFFu + ((u >> 16) & 1u)) >> 16;   // RNE
    return (unsigned short)r;
}
__device__ __forceinline__ float blo(unsigned int u) {        // low bf16 -> f32
    return __uint_as_float(u << 16);
}
__device__ __forceinline__ float bhi(unsigned int u) {        // high bf16 -> f32
    return __uint_as_float(u & 0xffff0000u);
}

// ---------------------------------------------------------------------------
// Fragment-packed layout for MFMA operands (both A and B use lane->(row=lc,
// kchunk=lq) for 16x16x32): element (n,k) of a [N][K] K-major matrix lives at
//   ((n>>4)*(K>>5) + (k>>5))*512 + ((k>>3)&3)*128 + (n&15)*8 + (k&7)
// so one bf16x8 load per lane = one contiguous 1KB wave transaction.
// ---------------------------------------------------------------------------

// ---------------------------------------------------------------------------
// Single-wave barrier-free bf16 MFMA GEMM, v2.
// Block = 1 wave, TM x 64 tile, fully-unrolled K (template), explicit 1-deep
// double-buffered prefetch: step s+1's 10-12 loads issue before step s's
// MFMAs, no barrier ever drains them (R7 lesson: occupancy is king — TM
// sized so every GEMM launches >=2048 waves = >=8/CU; R7's 4-6 waves/CU
// at TM=32/64 was the regression).
// B (weights) always fragment-packed; A optionally (AFRAG) — hb is packed
// by prep, epilogue-produced activations stay row-major.
// EPI: 0 bias->bf16 ; 1 bias+relu->bf16 ; 2 bias+res(f32)->f32 + stats ;
//      3 bias+res(bf16)->f32 + stats
// ---------------------------------------------------------------------------
template<int TM, int EPI, bool AFRAG, int K>
__global__ __launch_bounds__(64) void gemm_w2(
    const unsigned short* __restrict__ Xb, const unsigned short* __restrict__ Wt,
    const float* __restrict__ bias, const float* __restrict__ res,
    const unsigned short* __restrict__ resb,
    float* __restrict__ outf, unsigned short* __restrict__ outb,
    float* __restrict__ sum, float* __restrict__ sumsq, int Nc)
{
    constexpr int WM = TM / 16;     // 16-row mfma tiles per wave
    constexpr int KC = K >> 5;      // 32-elem k-chunks
    constexpr int NS = K >> 6;      // 64-elem k-steps
    const int lane = threadIdx.x;
    const int lc = lane & 15, lq = lane >> 4;
    const int m0 = blockIdx.y * TM, n0 = blockIdx.x * 64;

    const unsigned short* paf = Xb + ((size_t)(m0 >> 4) * KC) * 512 + lane * 8;
    const unsigned short* par = Xb + (size_t)(m0 + lc) * K + lq * 8;
    const unsigned short* pb  = Wt + ((size_t)(n0 >> 4) * KC) * 512 + lane * 8;

    bf16x8 af[2][WM][2], bfr[2][4][2];
    f32x4 acc[WM][4] = {};

    auto load_step = [&](int s, int buf) {
        #pragma unroll
        for (int i = 0; i < WM; ++i)
            #pragma unroll
            for (int h = 0; h < 2; ++h)
                af[buf][i][h] = AFRAG
                    ? *(const bf16x8*)(paf + ((size_t)i * KC + 2 * s + h) * 512)
                    : *(const bf16x8*)(par + (size_t)(i * 16) * K + s * 64 + h * 32);
        #pragma unroll
        for (int j = 0; j < 4; ++j)
            #pragma unroll
            for (int h = 0; h < 2; ++h)
                bfr[buf][j][h] = *(const bf16x8*)(pb + ((size_t)j * KC + 2 * s + h) * 512);
    };

    load_step(0, 0);
    #pragma unroll
    for (int s = 0; s < NS; ++s) {
        const int cur = s & 1;
        if (s + 1 < NS) load_step(s + 1, cur ^ 1);
        #pragma unroll
        for (int h = 0; h < 2; ++h)
            #pragma unroll
            for (int i = 0; i < WM; ++i)
                #pragma unroll
                for (int j = 0; j < 4; ++j)
                    acc[i][j] = __builtin_amdgcn_mfma_f32_16x16x32_bf16(
                        af[cur][i][h], bfr[cur][j][h], acc[i][j], 0, 0, 0);
    }

    float cs[4] = {}, css[4] = {};
    #pragma unroll
    for (int i = 0; i < WM; ++i) {
        #pragma unroll
        for (int j = 0; j < 4; ++j) {
            const int gr0 = m0 + i * 16 + lq * 4;
            const int gc = n0 + j * 16 + lc;
            const float bi = bias[gc];
            #pragma unroll
            for (int r = 0; r < 4; ++r) {
                float val = acc[i][j][r] + bi;
                size_t off = (size_t)(gr0 + r) * Nc + gc;
                if (EPI == 0)      outb[off] = f2bf(val);
                else if (EPI == 1) outb[off] = f2bf(fmaxf(val, 0.f));
                else {
                    if (EPI == 2) val += res[off];
                    else          val += blo((unsigned int)resb[off]);
                    outf[off] = val;
                    cs[j] += val; css[j] += val * val;
                }
            }
        }
    }
    if (EPI >= 2) {
        #pragma unroll
        for (int j = 0; j < 4; ++j) {
            float s = cs[j], ss = css[j];
            s += __shfl_xor(s, 16); s += __shfl_xor(s, 32);
            ss += __shfl_xor(ss, 16); ss += __shfl_xor(ss, 32);
            if (lq == 0) {
                const int gc = n0 + j * 16 + lc;
                atomicAdd(&sum[gc], s);
                atomicAdd(&sumsq[gc], ss);
            }
        }
    }
}

// ---------------------------------------------------------------------------
// Fused prep: z=0..5 weight transpose -> FRAGMENT-PACKED bf16;
// z=6 h -> fragment-packed bf16; z=7 bias concat + stat zero
// ---------------------------------------------------------------------------
__global__ __launch_bounds__(256) void prep_all(
    const float* __restrict__ Wq, const float* __restrict__ Wk,
    const float* __restrict__ Wv, const float* __restrict__ Wo,
    const float* __restrict__ W1, const float* __restrict__ W2,
    const float* __restrict__ h,
    const float* __restrict__ bq, const float* __restrict__ bk,
    const float* __restrict__ bv,
    unsigned short* __restrict__ wqkvT, unsigned short* __restrict__ woT,
    unsigned short* __restrict__ w1T, unsigned short* __restrict__ w2T,
    unsigned int* __restrict__ hb, float* __restrict__ bqkv,
    float* __restrict__ st)
{
    const int z = blockIdx.z;
    if (z < 6) {
        const float* in; unsigned short* out; int R, C;
        switch (z) {
            case 0: in = Wq; out = wqkvT;          R = 512;  C = 512;  break;
            case 1: in = Wk; out = wqkvT + 262144; R = 512;  C = 512;  break;
            case 2: in = Wv; out = wqkvT + 524288; R = 512;  C = 512;  break;
            case 3: in = Wo; out = woT;            R = 512;  C = 512;  break;
            case 4: in = W1; out = w1T;            R = 512;  C = 1024; break;
            default: in = W2; out = w2T;           R = 1024; C = 512;  break;
        }
        const int bc = blockIdx.x * 32, br = blockIdx.y * 32;
        if (bc >= C || br >= R) return;
        __shared__ float tile[32][33];
        const int tx = threadIdx.x & 31, ty = threadIdx.x >> 5;
        #pragma unroll
        for (int r = ty; r < 32; r += 8)
            tile[r][tx] = in[(size_t)(br + r) * C + bc + tx];
        __syncthreads();
        // frag-packed store: n = bc + r (out row / C-col), k = br + tx
        #pragma unroll
        for (int r = ty; r < 32; r += 8) {
            const int n = bc + r, k = br + tx;
            const size_t off = ((size_t)(n >> 4) * (R >> 5) + (k >> 5)) * 512
                             + ((k >> 3) & 3) * 128 + (n & 15) * 8 + (k & 7);
            out[off] = f2bf(tile[tx][r]);
        }
    } else if (z == 6) {
        // h (4096x512 f32) -> fragment-packed bf16 (K=512); thread converts
        // 8 consecutive k of one row = exactly one lane slot -> uint4 store
        const int blk = blockIdx.y * 32 + blockIdx.x;
        const int i = blk * 512 + threadIdx.x * 2;   // even float4 index
        const float4* in4 = (const float4*)h;
        float4 f0 = in4[i], f1 = in4[i + 1];
        uint4 w;
        w.x = (unsigned int)f2bf(f0.x) | ((unsigned int)f2bf(f0.y) << 16);
        w.y = (unsigned int)f2bf(f0.z) | ((unsigned int)f2bf(f0.w) << 16);
        w.z = (unsigned int)f2bf(f1.x) | ((unsigned int)f2bf(f1.y) << 16);
        w.w = (unsigned int)f2bf(f1.z) | ((unsigned int)f2bf(f1.w) << 16);
        const int m = i >> 7, k = (i & 127) * 4;     // k % 8 == 0
        const size_t off_u4 = ((size_t)(m >> 4) * 16 + (k >> 5)) * 64
                            + ((k >> 3) & 3) * 16 + (m & 15);
        ((uint4*)hb)[off_u4] = w;
    } else {
        const int blk = blockIdx.y * 32 + blockIdx.x;
        const int i = blk * 256 + threadIdx.x;
        if (i < 1536) bqkv[i] = i < 512 ? bq[i] : (i < 1024 ? bk[i - 512] : bv[i - 1024]);
        if (i < 2048) st[i] = 0.0f;
    }
}

// ---------------------------------------------------------------------------
// Sparse attention v5 (unchanged since R5: ~44us, 0 conflicts, stable).
// Inline adjacency build + dual-head gather loops with 1-deep prefetch.
// NO bulk K/V LDS staging (v3's 1-block/CU cliff: 123us vs 65us).
// ---------------------------------------------------------------------------
__global__ __launch_bounds__(256) void sparse_attn5(
    const float* __restrict__ A, const unsigned short* __restrict__ qkv,
    unsigned short* __restrict__ o)
{
    const int n = blockIdx.x;
    const int tid = threadIdx.x;
    const int wv = tid >> 6, lane = tid & 63;

    __shared__ int s_idx[MAXD];
    __shared__ float s_p[8][MAXD];
    __shared__ int s_cnt[4];

    // ---- Phase A: inline adjacency ----
    const float4* r4 = (const float4*)(A + (size_t)n * N_NODES);
    float4 av[4];
    #pragma unroll
    for (int t = 0; t < 4; ++t)
        av[t] = r4[wv * 256 + t * 64 + lane];

    const unsigned long long lt = (1ull << lane) - 1ull;
    int cnt = 0;
    #pragma unroll
    for (int t = 0; t < 4; ++t) {
        #pragma unroll
        for (int b = 0; b < 4; ++b) {
            float vb = (b == 0) ? av[t].x : (b == 1) ? av[t].y : (b == 2) ? av[t].z : av[t].w;
            cnt += __popcll(__ballot(vb > 0.0f));
        }
    }
    if (lane == 0) s_cnt[wv] = cnt;
    __syncthreads();
    int base = 0, total = 0;
    #pragma unroll
    for (int w = 0; w < 4; ++w) {
        if (w < wv) base += s_cnt[w];
        total += s_cnt[w];
    }
    const int d = total < MAXD ? total : MAXD;
    #pragma unroll
    for (int t = 0; t < 4; ++t) {
        #pragma unroll
        for (int b = 0; b < 4; ++b) {
            float vb = (b == 0) ? av[t].x : (b == 1) ? av[t].y : (b == 2) ? av[t].z : av[t].w;
            unsigned long long m = __ballot(vb > 0.0f);
            if (vb > 0.0f) {
                int p = base + __popcll(m & lt);
                if (p < MAXD) s_idx[p] = wv * 1024 + t * 256 + lane * 4 + b;
            }
            base += __popcll(m);
        }
    }
    __syncthreads();

    // ---- Phase B: attention ----
    const int jl = lane >> 3;
    const int dgs = lane & 7;
    const int jl2 = lane >> 4;
    const int dga = lane & 15;
    const int h0 = wv, h1 = wv + 4;

    const unsigned short* qp = qkv + (size_t)n * 1536 + dgs * 8;
    uint4 qa = *(const uint4*)(qp + h0 * 64);
    uint4 qb = *(const uint4*)(qp + h1 * 64);
    const float a0 = blo(qa.x), a1 = bhi(qa.x), a2 = blo(qa.y), a3 = bhi(qa.y);
    const float a4 = blo(qa.z), a5 = bhi(qa.z), a6 = blo(qa.w), a7 = bhi(qa.w);
    const float b0 = blo(qb.x), b1 = bhi(qb.x), b2 = blo(qb.y), b3 = bhi(qb.y);
    const float b4 = blo(qb.z), b5 = bhi(qb.z), b6 = blo(qb.w), b7 = bhi(qb.w);

    uint4 ka = {0, 0, 0, 0}, kb = {0, 0, 0, 0};
    if (jl < d) {
        const unsigned short* p = qkv + (size_t)s_idx[jl] * 1536 + 512 + dgs * 8;
        ka = *(const uint4*)(p + h0 * 64);
        kb = *(const uint4*)(p + h1 * 64);
    }
    for (int j0 = 0; j0 < d; j0 += 8) {
        const uint4 ca = ka, cb = kb;
        const int jn = j0 + 8 + jl;
        if (jn < d) {
            const unsigned short* p = qkv + (size_t)s_idx[jn] * 1536 + 512 + dgs * 8;
            ka = *(const uint4*)(p + h0 * 64);
            kb = *(const uint4*)(p + h1 * 64);
        }
        const int jc = j0 + jl;
        float s0 = 0.f, s1 = 0.f;
        if (jc < d) {
            s0 = a0 * blo(ca.x) + a1 * bhi(ca.x) + a2 * blo(ca.y) + a3 * bhi(ca.y)
               + a4 * blo(ca.z) + a5 * bhi(ca.z) + a6 * blo(ca.w) + a7 * bhi(ca.w);
            s1 = b0 * blo(cb.x) + b1 * bhi(cb.x) + b2 * blo(cb.y) + b3 * bhi(cb.y)
               + b4 * blo(cb.z) + b5 * bhi(cb.z) + b6 * blo(cb.w) + b7 * bhi(cb.w);
        }
        s0 += __shfl_xor(s0, 1); s1 += __shfl_xor(s1, 1);
        s0 += __shfl_xor(s0, 2); s1 += __shfl_xor(s1, 2);
        s0 += __shfl_xor(s0, 4); s1 += __shfl_xor(s1, 4);
        if (dgs == 0 && jc < d) {
            s_p[h0][jc] = s0 * 0.125f;
            s_p[h1][jc] = s1 * 0.125f;
        }
    }

    float inv0, inv1;
    #pragma unroll
    for (int hh = 0; hh < 2; ++hh) {
        float* sp = s_p[hh ? h1 : h0];
        float mx = -1e30f;
        for (int j = lane; j < d; j += 64) mx = fmaxf(mx, sp[j]);
        #pragma unroll
        for (int off = 32; off; off >>= 1) mx = fmaxf(mx, __shfl_xor(mx, off));
        float sum = 0.f;
        for (int j = lane; j < d; j += 64) {
            float e = __expf(sp[j] - mx);
            sp[j] = e;
            sum += e;
        }
        #pragma unroll
        for (int off = 32; off; off >>= 1) sum += __shfl_xor(sum, off);
        if (hh) inv1 = 1.0f / sum; else inv0 = 1.0f / sum;
    }

    float x0 = 0.f, x1 = 0.f, x2 = 0.f, x3 = 0.f;
    float y0 = 0.f, y1 = 0.f, y2 = 0.f, y3 = 0.f;
    uint2 va = {0, 0}, vb = {0, 0};
    if (jl2 < d) {
        const unsigned short* p = qkv + (size_t)s_idx[jl2] * 1536 + 1024 + dga * 4;
        va = *(const uint2*)(p + h0 * 64);
        vb = *(const uint2*)(p + h1 * 64);
    }
    for (int j0 = 0; j0 < d; j0 += 4) {
        const uint2 ca = va, cb = vb;
        const int jn = j0 + 4 + jl2;
        if (jn < d) {
            const unsigned short* p = qkv + (size_t)s_idx[jn] * 1536 + 1024 + dga * 4;
            va = *(const uint2*)(p + h0 * 64);
            vb = *(const uint2*)(p + h1 * 64);
        }
        const int jc = j0 + jl2;
        if (jc < d) {
            const float p0 = s_p[h0][jc], p1 = s_p[h1][jc];
            x0 += p0 * blo(ca.x); x1 += p0 * bhi(ca.x);
            x2 += p0 * blo(ca.y); x3 += p0 * bhi(ca.y);
            y0 += p1 * blo(cb.x); y1 += p1 * bhi(cb.x);
            y2 += p1 * blo(cb.y); y3 += p1 * bhi(cb.y);
        }
    }
    x0 += __shfl_xor(x0, 16); x0 += __shfl_xor(x0, 32);
    x1 += __shfl_xor(x1, 16); x1 += __shfl_xor(x1, 32);
    x2 += __shfl_xor(x2, 16); x2 += __shfl_xor(x2, 32);
    x3 += __shfl_xor(x3, 16); x3 += __shfl_xor(x3, 32);
    y0 += __shfl_xor(y0, 16); y0 += __shfl_xor(y0, 32);
    y1 += __shfl_xor(y1, 16); y1 += __shfl_xor(y1, 32);
    y2 += __shfl_xor(y2, 16); y2 += __shfl_xor(y2, 32);
    y3 += __shfl_xor(y3, 16); y3 += __shfl_xor(y3, 32);
    if (jl2 == 0) {
        uint2 w0, w1;
        w0.x = (unsigned int)f2bf(x0 * inv0) | ((unsigned int)f2bf(x1 * inv0) << 16);
        w0.y = (unsigned int)f2bf(x2 * inv0) | ((unsigned int)f2bf(x3 * inv0) << 16);
        w1.x = (unsigned int)f2bf(y0 * inv1) | ((unsigned int)f2bf(y1 * inv1) << 16);
        w1.y = (unsigned int)f2bf(y2 * inv1) | ((unsigned int)f2bf(y3 * inv1) << 16);
        *(uint2*)(o + (size_t)n * 512 + h0 * 64 + dga * 4) = w0;
        *(uint2*)(o + (size_t)n * 512 + h1 * 64 + dga * 4) = w1;
    }
}

// ---------------------------------------------------------------------------
// BatchNorm apply, float4 (stats fused in the preceding GEMM epilogue).
// ---------------------------------------------------------------------------
__global__ __launch_bounds__(256) void bn_apply4(
    const float4* __restrict__ x, const float* __restrict__ sum,
    const float* __restrict__ sumsq, const float* __restrict__ g,
    const float* __restrict__ b, float4* __restrict__ yf,
    uint2* __restrict__ yb)
{
    const int i = blockIdx.x * 256 + threadIdx.x;
    const int c4 = i & 127;
    const float4 s4 = ((const float4*)sum)[c4];
    const float4 q4 = ((const float4*)sumsq)[c4];
    const float4 g4 = ((const float4*)g)[c4];
    const float4 b4 = ((const float4*)b)[c4];
    const float4 xv = x[i];
    const float kN = 1.0f / N_NODES;
    float4 r;
    { float m = s4.x * kN; r.x = g4.x * (xv.x - m) * rsqrtf(q4.x * kN - m * m + EPS) + b4.x; }
    { float m = s4.y * kN; r.y = g4.y * (xv.y - m) * rsqrtf(q4.y * kN - m * m + EPS) + b4.y; }
    { float m = s4.z * kN; r.z = g4.z * (xv.z - m) * rsqrtf(q4.z * kN - m * m + EPS) + b4.z; }
    { float m = s4.w * kN; r.w = g4.w * (xv.w - m) * rsqrtf(q4.w * kN - m * m + EPS) + b4.w; }
    if (yf) yf[i] = r;
    if (yb) {
        uint2 p;
        p.x = (unsigned int)f2bf(r.x) | ((unsigned int)f2bf(r.y) << 16);
        p.y = (unsigned int)f2bf(r.z) | ((unsigned int)f2bf(r.w) << 16);
        yb[i] = p;
    }
}

// ---------------------------------------------------------------------------

extern "C" void kernel_launch(void* const* d_in, const int* in_sizes, int n_in,
                              void* d_out, int out_size, void* d_ws, size_t ws_size,
                              hipStream_t stream)
{
    const float* A   = (const float*)d_in[0];
    const float* h   = (const float*)d_in[1];
    const float* Wq  = (const float*)d_in[2];
    const float* bq  = (const float*)d_in[3];
    const float* Wk  = (const float*)d_in[4];
    const float* bk  = (const float*)d_in[5];
    const float* Wv  = (const float*)d_in[6];
    const float* bv  = (const float*)d_in[7];
    const float* Wo  = (const float*)d_in[8];
    const float* bo  = (const float*)d_in[9];
    const float* g1  = (const float*)d_in[10];
    const float* b1g = (const float*)d_in[11];
    const float* g2  = (const float*)d_in[12];
    const float* b2g = (const float*)d_in[13];
    const float* W1  = (const float*)d_in[14];
    const float* b1  = (const float*)d_in[15];
    const float* W2  = (const float*)d_in[16];
    const float* b2  = (const float*)d_in[17];
    float* out = (float*)d_out;

    float* ws = (float*)d_ws;
    unsigned short* hb    = (unsigned short*)(ws);               // 4096x512 bf16 (frag)
    unsigned short* qkvb  = (unsigned short*)(ws + 1048576);     // 4096x1536 bf16
    unsigned short* o_bf  = (unsigned short*)(ws + 4194304);     // 4096x512 bf16
    unsigned short* wqkvT = (unsigned short*)(ws + 5242880);     // 1536x512 bf16 (frag)
    unsigned short* woT   = (unsigned short*)(ws + 5636096);     // 512x512 bf16 (frag)
    unsigned short* w1T   = (unsigned short*)(ws + 5767168);     // 1024x512 bf16 (frag)
    unsigned short* w2T   = (unsigned short*)(ws + 6029312);     // 512x1024 bf16 (frag)
    unsigned short* t_b   = (unsigned short*)(ws + 6291456);     // 4096x1024 bf16
    float* x1   = ws + 8388608;                                   // 4096x512 f32
    float* x2   = ws + 10485760;                                  // 4096x512 f32
    unsigned short* xb1_b = (unsigned short*)(ws + 12582912);    // 4096x512 bf16
    float* bqkv = ws + 13631488;                                  // 1536
    float* st   = ws + 13633024;                                  // 2048

    // --- fused prep (frag-packed weights + hb) ---
    prep_all<<<dim3(32, 32, 8), dim3(256), 0, stream>>>(
        Wq, Wk, Wv, Wo, W1, W2, h, bq, bk, bv,
        wqkvT, woT, w1T, w2T, (unsigned int*)hb, bqkv, st);

    // --- fused QKV projection: 3072 waves (12/CU) ---
    gemm_w2<32, 0, true, 512><<<dim3(24, 128), dim3(64), 0, stream>>>(
        hb, wqkvT, bqkv, nullptr, nullptr, nullptr, qkvb, nullptr, nullptr, 1536);

    // --- sparse masked attention (inline adjacency) ---
    sparse_attn5<<<dim3(N_NODES), dim3(256), 0, stream>>>(A, qkvb, o_bf);

    // --- O projection + residual(h,f32) + BN1 stats: 2048 waves (8/CU) ---
    gemm_w2<16, 2, false, 512><<<dim3(8, 256), dim3(64), 0, stream>>>(
        o_bf, woT, bo, h, nullptr, x1, nullptr, st, st + 512, 512);

    // --- BN1 apply -> bf16 only ---
    bn_apply4<<<dim3(2048), dim3(256), 0, stream>>>(
        (const float4*)x1, st, st + 512, g1, b1g, nullptr, (uint2*)xb1_b);

    // --- FFN1: 2048 waves (8/CU) ---
    gemm_w2<32, 1, false, 512><<<dim3(16, 128), dim3(64), 0, stream>>>(
        xb1_b, w1T, b1, nullptr, nullptr, nullptr, t_b, nullptr, nullptr, 1024);

    // --- FFN2 + residual(xb1,bf16) + BN2 stats: 2048 waves (8/CU) ---
    gemm_w2<16, 3, false, 1024><<<dim3(8, 256), dim3(64), 0, stream>>>(
        t_b, w2T, b2, nullptr, xb1_b, x2, nullptr, st + 1024, st + 1536, 512);

    // --- BN2 apply -> out ---
    bn_apply4<<<dim3(2048), dim3(256), 0, stream>>>(
        (const float4*)x2, st + 1024, st + 1536, g2, b2g, (float4*)out, nullptr);

    (void)in_sizes; (void)n_in; (void)out_size; (void)ws_size;
}